// Round 11
// baseline (78.099 us; speedup 1.0000x reference)
//
#include <hip/hip_runtime.h>
#include <hip/hip_bf16.h>

// Q8_0-style fused dequant + linear: y[32,11008] = x[32,4096] @ W^T + bias
// W[o,i] = (qweight[o,i] - 127) * scales[o, i/32]
//
// Round 11: ONE kernel, nothing else.
//  Findings r3-r10: the W-stream GEMM core runs ~4.6-4.9 TB/s effective under
//  every staging scheme tried (reg stream / LDS tile / global_load_lds bursts /
//  counted-vmcnt ring). The remaining time was the scaffolding: convert kernel,
//  reduce kernel, 2 graph gaps, partial round-trip. So: eliminate all of it.
//  - 1 wave = 16 o-rows x FULL K=4096. 688 single-wave blocks (11008/16),
//    ~2.7 waves/CU, every CU covered. No split-K -> no partials, no reduce.
//  - x read as f32 from global (L2-resident, 512 KB) + in-register bf16 cvt
//    -> no convert kernel, no d_ws at all.
//  - bias fused into the output store (f32 accumulate end-to-end, no f16
//    partial rounding).
//  - Register double-buffer (sets A/B, unroll-2), 25 loads (12 KB) in flight
//    during each chunk's dequant+MFMA; compiler inserts the counted vmcnt
//    (r10 proved manual asm waits buy nothing over this).

#define O_DIM 11008
#define I_DIM 4096
#define NB    128       // scale blocks per o-row
#define NCH   32        // chunks of 128 k

typedef __attribute__((ext_vector_type(8))) short bf16x8;
typedef __attribute__((ext_vector_type(4))) float f32x4;
typedef __attribute__((ext_vector_type(4))) int   i32x4;

static __device__ __forceinline__ unsigned short f2bf(float f) {
    return __builtin_bit_cast(unsigned short, __float2bfloat16(f));
}

static __device__ __forceinline__ bf16x8 dequant8(const i32x4 qa, const i32x4 qb,
                                                  const float s) {
    const float c = -127.0f * s;
    bf16x8 v;
    v[0] = (short)f2bf(fmaf((float)qa[0], s, c));
    v[1] = (short)f2bf(fmaf((float)qa[1], s, c));
    v[2] = (short)f2bf(fmaf((float)qa[2], s, c));
    v[3] = (short)f2bf(fmaf((float)qa[3], s, c));
    v[4] = (short)f2bf(fmaf((float)qb[0], s, c));
    v[5] = (short)f2bf(fmaf((float)qb[1], s, c));
    v[6] = (short)f2bf(fmaf((float)qb[2], s, c));
    v[7] = (short)f2bf(fmaf((float)qb[3], s, c));
    return v;
}

static __device__ __forceinline__ bf16x8 cvt8(const f32x4 lo, const f32x4 hi) {
    bf16x8 v;
    v[0] = (short)f2bf(lo[0]); v[1] = (short)f2bf(lo[1]);
    v[2] = (short)f2bf(lo[2]); v[3] = (short)f2bf(lo[3]);
    v[4] = (short)f2bf(hi[0]); v[5] = (short)f2bf(hi[1]);
    v[6] = (short)f2bf(hi[2]); v[7] = (short)f2bf(hi[3]);
    return v;
}

#define MFMA __builtin_amdgcn_mfma_f32_16x16x32_bf16

// issue one chunk's loads: 8x W dwordx4, 16x x float4, 1x scales float4
#define ISSUE(W, X, SC, c) {                                   \
    const int*   wp = wq + (size_t)(c) * 128;                  \
    const float* pa = xa + (size_t)(c) * 128;                  \
    const float* pb = xb + (size_t)(c) * 128;                  \
    _Pragma("unroll")                                          \
    for (int j = 0; j < 4; ++j) {                              \
        W[2*j]   = *(const i32x4*)(wp + j*32);                 \
        W[2*j+1] = *(const i32x4*)(wp + j*32 + 4);             \
        X[4*j]   = *(const f32x4*)(pa + j*32);                 \
        X[4*j+1] = *(const f32x4*)(pa + j*32 + 4);             \
        X[4*j+2] = *(const f32x4*)(pb + j*32);                 \
        X[4*j+3] = *(const f32x4*)(pb + j*32 + 4);             \
    }                                                          \
    SC = *(const f32x4*)(sp + (c) * 4);                        \
}

// consume one chunk: 4 k-steps x (dequant + cvt + 2 MFMA)
#define COMP(W, X, SC) {                                       \
    _Pragma("unroll")                                          \
    for (int j = 0; j < 4; ++j) {                              \
        const bf16x8 bb = dequant8(W[2*j], W[2*j+1], SC[j]);   \
        const bf16x8 a0 = cvt8(X[4*j],   X[4*j+1]);            \
        const bf16x8 a1 = cvt8(X[4*j+2], X[4*j+3]);            \
        acc0 = MFMA(a0, bb, acc0, 0, 0, 0);                    \
        acc1 = MFMA(a1, bb, acc1, 0, 0, 0);                    \
    }                                                          \
}

__global__ __launch_bounds__(64) void gemm_kernel(const float* __restrict__ x,
                                                  const int*   __restrict__ qw,
                                                  const float* __restrict__ scales,
                                                  const float* __restrict__ bias,
                                                  float*       __restrict__ out) {
    const int lan  = threadIdx.x;       // single wave per block
    const int lrow = lan & 15;          // fragment row
    const int lq   = lan >> 4;          // lane quarter -> k sub-offset

    const int o_row = blockIdx.x * 16 + lrow;   // 688 blocks x 16 o-rows

    const int*   __restrict__ wq = qw + (size_t)o_row * I_DIM + lq * 8;
    const float* __restrict__ xa = x  + (size_t)lrow  * I_DIM + lq * 8;
    const float* __restrict__ xb = xa + (size_t)16 * I_DIM;
    const float* __restrict__ sp = scales + (size_t)o_row * NB;

    i32x4 Aw[8], Bw[8];
    f32x4 Ax[16], Bx[16];
    f32x4 Asc, Bsc;
    f32x4 acc0 = {0.f, 0.f, 0.f, 0.f};   // m rows 0..15
    f32x4 acc1 = {0.f, 0.f, 0.f, 0.f};   // m rows 16..31

    ISSUE(Aw, Ax, Asc, 0)
    ISSUE(Bw, Bx, Bsc, 1)

    for (int c = 0; c < NCH - 2; c += 2) {
        COMP(Aw, Ax, Asc)
        ISSUE(Aw, Ax, Asc, c + 2)
        COMP(Bw, Bx, Bsc)
        ISSUE(Bw, Bx, Bsc, c + 3)
    }
    COMP(Aw, Ax, Asc)    // chunk 30
    COMP(Bw, Bx, Bsc)    // chunk 31

    // C/D layout: col(o) = lane&15, row(m) = lq*4 + reg (acc0), +16 (acc1) [m89]
    const float bv = bias[o_row];
#pragma unroll
    for (int r = 0; r < 4; ++r) {
        out[(size_t)(lq * 4 + r) * O_DIM + o_row]        = acc0[r] + bv;
        out[(size_t)(lq * 4 + r + 16) * O_DIM + o_row]   = acc1[r] + bv;
    }
}

extern "C" void kernel_launch(void* const* d_in, const int* in_sizes, int n_in,
                              void* d_out, int out_size, void* d_ws, size_t ws_size,
                              hipStream_t stream) {
    const float* x      = (const float*)d_in[0];
    const int*   qw     = (const int*)d_in[1];
    const float* scales = (const float*)d_in[2];
    const float* bias   = (const float*)d_in[3];
    float*       out    = (float*)d_out;

    // single kernel: full-K per wave, direct bias-fused output
    hipLaunchKernelGGL(gemm_kernel, dim3(O_DIM / 16), dim3(64), 0, stream,
                       x, qw, scales, bias, out);
}

// Round 12
// 51.310 us; speedup vs baseline: 1.5221x; 1.5221x over previous
//
#include <hip/hip_runtime.h>
#include <hip/hip_bf16.h>

// Q8_0-style fused dequant + linear: y[32,11008] = x[32,4096] @ W^T + bias
// W[o,i] = (qweight[o,i] - 127) * scales[o, i/32]
//
// Round 12 = round 5's GEMM core (best measured: 47.1us total, core ~4.5TB/s)
// with the partial/reduce scaffolding replaced by an atomic epilogue:
//  - k1: out = bias (row broadcast), 1.4 MB fill (~0.4us). Re-run every call
//    so graph replays stay correct.
//  - k2: r5 GEMM verbatim (NSPLIT=16, KT=256, 16KB swizzled LDS x-tile,
//    3-buffer register W pipeline, barrier-free k-loop, split-major grid);
//    epilogue = f32 atomicAdd into out (r3 vs r4 proved atomics ~free).
//  - No partial buffer, no reduce kernel, one less launch gap.

#define O_DIM  11008
#define I_DIM  4096
#define NB     128                // scale blocks per o-row
#define B_DIM  32
#define NSPLIT 16
#define KT     (I_DIM / NSPLIT)   // 256

typedef __attribute__((ext_vector_type(8))) short bf16x8;
typedef __attribute__((ext_vector_type(4))) float f32x4;
typedef __attribute__((ext_vector_type(4))) int   i32x4;

static __device__ __forceinline__ unsigned short f2bf(float f) {
    return __builtin_bit_cast(unsigned short, __float2bfloat16(f));
}

static __device__ __forceinline__ bf16x8 dequant8(const i32x4 qa, const i32x4 qb,
                                                  const float s) {
    const float c = -127.0f * s;
    bf16x8 v;
    v[0] = (short)f2bf(fmaf((float)qa[0], s, c));
    v[1] = (short)f2bf(fmaf((float)qa[1], s, c));
    v[2] = (short)f2bf(fmaf((float)qa[2], s, c));
    v[3] = (short)f2bf(fmaf((float)qa[3], s, c));
    v[4] = (short)f2bf(fmaf((float)qb[0], s, c));
    v[5] = (short)f2bf(fmaf((float)qb[1], s, c));
    v[6] = (short)f2bf(fmaf((float)qb[2], s, c));
    v[7] = (short)f2bf(fmaf((float)qb[3], s, c));
    return v;
}

// ---- k1: out[m][o] = bias[o] ----
__global__ __launch_bounds__(256) void bias_fill_kernel(const float* __restrict__ bias,
                                                        float* __restrict__ out) {
    const int idx = blockIdx.x * 256 + threadIdx.x;   // 344 blocks = 88064 float4s
    const int m   = idx / (O_DIM / 4);
    const int o4  = (idx - m * (O_DIM / 4)) * 4;
    const f32x4 b = *reinterpret_cast<const f32x4*>(&bias[o4]);
    *reinterpret_cast<f32x4*>(&out[(size_t)m * O_DIM + o4]) = b;
}

__global__ __launch_bounds__(256) void gemm_kernel(const float* __restrict__ x,
                                                   const int*   __restrict__ qw,
                                                   const float* __restrict__ scales,
                                                   float*       __restrict__ out) {
    __shared__ unsigned short x_s[B_DIM * KT];   // 16 KB, XOR-swizzled

    const int t    = threadIdx.x;
    const int wav  = t >> 6;
    const int lan  = t & 63;
    const int lrow = lan & 15;      // fragment row
    const int lq   = lan >> 4;      // lane quarter -> k sub-offset

    const int split  = blockIdx.x;                    // fastest-varying: k-split
    const int k_base = split * KT;
    const int o_row  = blockIdx.y * 64 + wav * 16 + lrow;

    const int* __restrict__ wq = qw + (size_t)o_row * I_DIM + k_base + lq * 8;

    // 8 scales for this row's k-split (one per 32-k step)
    float sc[8];
    {
        const float4* sp = reinterpret_cast<const float4*>(&scales[o_row * NB + split * 8]);
        const float4 s0 = sp[0], s1 = sp[1];
        sc[0] = s0.x; sc[1] = s0.y; sc[2] = s0.z; sc[3] = s0.w;
        sc[4] = s1.x; sc[5] = s1.y; sc[6] = s1.z; sc[7] = s1.w;
    }

    // chunk = 64 k (2 MFMA k-steps); lane's W slice = 2x 16B at +0/+16B
    i32x4 wa0, wb0, wc0, wd0, wa1, wb1, wc1, wd1, wa2, wb2, wc2, wd2;

#define LOADW(A, B, C, D, c) {                           \
        const int* wp = wq + (c) * 64;                   \
        A = *reinterpret_cast<const i32x4*>(wp);         \
        B = *reinterpret_cast<const i32x4*>(wp + 4);     \
        C = *reinterpret_cast<const i32x4*>(wp + 32);    \
        D = *reinterpret_cast<const i32x4*>(wp + 36); }

    // issue first 2 chunks before staging/barrier (they don't touch LDS)
    LOADW(wa0, wb0, wc0, wd0, 0)
    LOADW(wa1, wb1, wc1, wd1, 1)

    // ---- stage x once: f32 global -> bf16 swizzled LDS ----
    {
        const int m  = t >> 3;            // 0..31
        const int k0 = (t & 7) * 32;      // 0..224
        const float4* xv = reinterpret_cast<const float4*>(x + m * I_DIM + k_base + k0);
#pragma unroll
        for (int j = 0; j < 4; ++j) {
            const float4 va = xv[2 * j];
            const float4 vb = xv[2 * j + 1];
            bf16x8 v;
            v[0] = (short)f2bf(va.x); v[1] = (short)f2bf(va.y);
            v[2] = (short)f2bf(va.z); v[3] = (short)f2bf(va.w);
            v[4] = (short)f2bf(vb.x); v[5] = (short)f2bf(vb.y);
            v[6] = (short)f2bf(vb.z); v[7] = (short)f2bf(vb.w);
            const int addr = ((m * KT + k0 + j * 8) * 2) ^ ((m & 7) << 4);
            *reinterpret_cast<bf16x8*>(reinterpret_cast<char*>(x_s) + addr) = v;
        }
    }

    __syncthreads();

    f32x4 acc0 = {0.f, 0.f, 0.f, 0.f};   // m rows 0..15
    f32x4 acc1 = {0.f, 0.f, 0.f, 0.f};   // m rows 16..31
    const int swz = (lrow & 7) << 4;

#define CONSUME(A, B, C, D, c) {                                                              \
        const int kb = (c) * 64 + lq * 8;                                                     \
        const bf16x8 a0 = *reinterpret_cast<const bf16x8*>(                                   \
            reinterpret_cast<const char*>(x_s) + ((( lrow       * KT + kb) * 2) ^ swz));      \
        const bf16x8 a1 = *reinterpret_cast<const bf16x8*>(                                   \
            reinterpret_cast<const char*>(x_s) + ((((lrow + 16) * KT + kb) * 2) ^ swz));      \
        const bf16x8 bA = dequant8(A, B, sc[2 * (c)]);                                        \
        acc0 = __builtin_amdgcn_mfma_f32_16x16x32_bf16(a0, bA, acc0, 0, 0, 0);                \
        acc1 = __builtin_amdgcn_mfma_f32_16x16x32_bf16(a1, bA, acc1, 0, 0, 0);                \
        const bf16x8 a2 = *reinterpret_cast<const bf16x8*>(                                   \
            reinterpret_cast<const char*>(x_s) + ((( lrow       * KT + kb + 32) * 2) ^ swz)); \
        const bf16x8 a3 = *reinterpret_cast<const bf16x8*>(                                   \
            reinterpret_cast<const char*>(x_s) + ((((lrow + 16) * KT + kb + 32) * 2) ^ swz)); \
        const bf16x8 bB = dequant8(C, D, sc[2 * (c) + 1]);                                    \
        acc0 = __builtin_amdgcn_mfma_f32_16x16x32_bf16(a2, bB, acc0, 0, 0, 0);                \
        acc1 = __builtin_amdgcn_mfma_f32_16x16x32_bf16(a3, bB, acc1, 0, 0, 0); }

    // 4 chunks, 3 buffers: consume c with chunks c+1, c+2 in flight
    LOADW(wa2, wb2, wc2, wd2, 2)
    CONSUME(wa0, wb0, wc0, wd0, 0)
    LOADW(wa0, wb0, wc0, wd0, 3)
    CONSUME(wa1, wb1, wc1, wd1, 1)
    CONSUME(wa2, wb2, wc2, wd2, 2)
    CONSUME(wa0, wb0, wc0, wd0, 3)

#undef LOADW
#undef CONSUME

    // ---- epilogue: f32 atomicAdd into bias-pre-initialized out ----
    // C/D layout: col(o) = lane&15, row(m) = lq*4 + reg (acc0), +16 (acc1) [m89]
#pragma unroll
    for (int r = 0; r < 4; ++r) {
        const int m = lq * 4 + r;
        atomicAdd(&out[(size_t)m * O_DIM + o_row],        acc0[r]);
        atomicAdd(&out[(size_t)(m + 16) * O_DIM + o_row], acc1[r]);
    }
}

extern "C" void kernel_launch(void* const* d_in, const int* in_sizes, int n_in,
                              void* d_out, int out_size, void* d_ws, size_t ws_size,
                              hipStream_t stream) {
    const float* x      = (const float*)d_in[0];
    const int*   qw     = (const int*)d_in[1];
    const float* scales = (const float*)d_in[2];
    const float* bias   = (const float*)d_in[3];
    float*       out    = (float*)d_out;

    // k1: out = bias (re-runs every call -> replay-safe)
    hipLaunchKernelGGL(bias_fill_kernel, dim3((B_DIM * O_DIM / 4) / 256), dim3(256),
                       0, stream, bias, out);

    // k2: streaming dequant-MFMA GEMM (r5 core), atomic split-K combine
    hipLaunchKernelGGL(gemm_kernel, dim3(NSPLIT, O_DIM / 64), dim3(256), 0, stream,
                       x, qw, scales, out);
}

// Round 13
// 47.570 us; speedup vs baseline: 1.6417x; 1.0786x over previous
//
#include <hip/hip_runtime.h>
#include <hip/hip_bf16.h>

// Q8_0-style fused dequant + linear: y[32,11008] = x[32,4096] @ W^T + bias
// W[o,i] = (qweight[o,i] - 127) * scales[o, i/32]
//
// Round 13 = byte-identical resubmission of round 5 (best measured: 47.1 us).
// Seven structurally different engines (r2-r12) all landed 47-51 us with the
// W-stream core pinned at ~4.4-4.6 TB/s effective; r5 is the best point.
//  - k1 (gemm): block = 64 o x 32 b x k-split of 256 (NSPLIT=16, split-major).
//    x slice f32->bf16 staged once in XOR-swizzled LDS (16 KB), single
//    __syncthreads; barrier-free k-loop, W read once from global via a
//    3-buffer register chunk pipeline, dequant in registers, bf16 MFMA.
//  - k2 (reduce): out = bias + sum of 16 f32 partials (coalesced).

#define O_DIM  11008
#define I_DIM  4096
#define NB     128                // scale blocks per o-row
#define B_DIM  32
#define NSPLIT 16
#define KT     (I_DIM / NSPLIT)   // 256
#define PART_STRIDE (B_DIM * O_DIM)

typedef __attribute__((ext_vector_type(8))) short bf16x8;
typedef __attribute__((ext_vector_type(4))) float f32x4;

static __device__ __forceinline__ unsigned short f2bf(float f) {
    return __builtin_bit_cast(unsigned short, __float2bfloat16(f));
}

static __device__ __forceinline__ bf16x8 dequant8(const int4 qa, const int4 qb,
                                                  const float s) {
    const float c = -127.0f * s;
    bf16x8 v;
    v[0] = (short)f2bf(fmaf((float)qa.x, s, c));
    v[1] = (short)f2bf(fmaf((float)qa.y, s, c));
    v[2] = (short)f2bf(fmaf((float)qa.z, s, c));
    v[3] = (short)f2bf(fmaf((float)qa.w, s, c));
    v[4] = (short)f2bf(fmaf((float)qb.x, s, c));
    v[5] = (short)f2bf(fmaf((float)qb.y, s, c));
    v[6] = (short)f2bf(fmaf((float)qb.z, s, c));
    v[7] = (short)f2bf(fmaf((float)qb.w, s, c));
    return v;
}

__global__ __launch_bounds__(256) void gemm_kernel(const float* __restrict__ x,
                                                   const int*   __restrict__ qw,
                                                   const float* __restrict__ scales,
                                                   float*       __restrict__ part) {
    __shared__ unsigned short x_s[B_DIM * KT];   // 16 KB, XOR-swizzled

    const int t    = threadIdx.x;
    const int wav  = t >> 6;
    const int lan  = t & 63;
    const int lrow = lan & 15;      // fragment row
    const int lq   = lan >> 4;      // lane quarter -> k sub-offset

    const int split  = blockIdx.x;                    // fastest-varying: k-split
    const int k_base = split * KT;
    const int o_row  = blockIdx.y * 64 + wav * 16 + lrow;

    const int* __restrict__ wq = qw + o_row * I_DIM + k_base + lq * 8;

    // 8 scales for this row's k-split (one per 32-k step)
    float sc[8];
    {
        const float4* sp = reinterpret_cast<const float4*>(&scales[o_row * NB + split * 8]);
        const float4 s0 = sp[0], s1 = sp[1];
        sc[0] = s0.x; sc[1] = s0.y; sc[2] = s0.z; sc[3] = s0.w;
        sc[4] = s1.x; sc[5] = s1.y; sc[6] = s1.z; sc[7] = s1.w;
    }

    // chunk = 64 k (2 MFMA k-steps); lane's W slice = 2x 32B contiguous
    int4 wa0, wb0, wc0, wd0, wa1, wb1, wc1, wd1, wa2, wb2, wc2, wd2;

#define LOADW(A, B, C, D, c) {                         \
        const int* wp = wq + (c) * 64;                 \
        A = *reinterpret_cast<const int4*>(wp);        \
        B = *reinterpret_cast<const int4*>(wp + 4);    \
        C = *reinterpret_cast<const int4*>(wp + 32);   \
        D = *reinterpret_cast<const int4*>(wp + 36); }

    // issue first 2 chunks before the barrier (they don't touch LDS)
    LOADW(wa0, wb0, wc0, wd0, 0)
    LOADW(wa1, wb1, wc1, wd1, 1)

    // ---- stage x once: f32 global -> bf16 swizzled LDS ----
    {
        const int m  = t >> 3;            // 0..31
        const int k0 = (t & 7) * 32;      // 0..224
        const float4* xv = reinterpret_cast<const float4*>(x + m * I_DIM + k_base + k0);
#pragma unroll
        for (int j = 0; j < 4; ++j) {
            const float4 va = xv[2 * j];
            const float4 vb = xv[2 * j + 1];
            bf16x8 v;
            v[0] = (short)f2bf(va.x); v[1] = (short)f2bf(va.y);
            v[2] = (short)f2bf(va.z); v[3] = (short)f2bf(va.w);
            v[4] = (short)f2bf(vb.x); v[5] = (short)f2bf(vb.y);
            v[6] = (short)f2bf(vb.z); v[7] = (short)f2bf(vb.w);
            const int addr = ((m * KT + k0 + j * 8) * 2) ^ ((m & 7) << 4);
            *reinterpret_cast<bf16x8*>(reinterpret_cast<char*>(x_s) + addr) = v;
        }
    }

    __syncthreads();

    f32x4 acc0 = {0.f, 0.f, 0.f, 0.f};   // m rows 0..15
    f32x4 acc1 = {0.f, 0.f, 0.f, 0.f};   // m rows 16..31
    const int swz = (lrow & 7) << 4;

#define CONSUME(A, B, C, D, c) {                                                              \
        const int kb = (c) * 64 + lq * 8;                                                     \
        const bf16x8 a0 = *reinterpret_cast<const bf16x8*>(                                   \
            reinterpret_cast<const char*>(x_s) + ((( lrow       * KT + kb) * 2) ^ swz));      \
        const bf16x8 a1 = *reinterpret_cast<const bf16x8*>(                                   \
            reinterpret_cast<const char*>(x_s) + ((((lrow + 16) * KT + kb) * 2) ^ swz));      \
        const bf16x8 bA = dequant8(A, B, sc[2 * (c)]);                                        \
        acc0 = __builtin_amdgcn_mfma_f32_16x16x32_bf16(a0, bA, acc0, 0, 0, 0);                \
        acc1 = __builtin_amdgcn_mfma_f32_16x16x32_bf16(a1, bA, acc1, 0, 0, 0);                \
        const bf16x8 a2 = *reinterpret_cast<const bf16x8*>(                                   \
            reinterpret_cast<const char*>(x_s) + ((( lrow       * KT + kb + 32) * 2) ^ swz)); \
        const bf16x8 a3 = *reinterpret_cast<const bf16x8*>(                                   \
            reinterpret_cast<const char*>(x_s) + ((((lrow + 16) * KT + kb + 32) * 2) ^ swz)); \
        const bf16x8 bB = dequant8(C, D, sc[2 * (c) + 1]);                                    \
        acc0 = __builtin_amdgcn_mfma_f32_16x16x32_bf16(a2, bB, acc0, 0, 0, 0);                \
        acc1 = __builtin_amdgcn_mfma_f32_16x16x32_bf16(a3, bB, acc1, 0, 0, 0); }

    // 4 chunks, 3 buffers: consume c with chunks c+1, c+2 in flight
    LOADW(wa2, wb2, wc2, wd2, 2)
    CONSUME(wa0, wb0, wc0, wd0, 0)
    LOADW(wa0, wb0, wc0, wd0, 3)
    CONSUME(wa1, wb1, wc1, wd1, 1)
    CONSUME(wa2, wb2, wc2, wd2, 2)
    CONSUME(wa0, wb0, wc0, wd0, 3)

#undef LOADW
#undef CONSUME

    // C/D layout: col = lane&15 (o), row = (lane>>4)*4 + reg (m)  [m89]
    float* pp = part + split * PART_STRIDE;
#pragma unroll
    for (int r = 0; r < 4; ++r) {
        const int m = lq * 4 + r;
        pp[m * O_DIM + o_row]        = acc0[r];
        pp[(m + 16) * O_DIM + o_row] = acc1[r];
    }
}

// ---- k2: out = bias + sum of partials ----
__global__ __launch_bounds__(256) void reduce_kernel(const float* __restrict__ part,
                                                     const float* __restrict__ bias,
                                                     float* __restrict__ out) {
    const int o = blockIdx.x * 256 + threadIdx.x;   // grid.x = 43
    const int m = blockIdx.y;                        // grid.y = 32
    float v = bias[o];
#pragma unroll
    for (int s = 0; s < NSPLIT; ++s)
        v += part[s * PART_STRIDE + m * O_DIM + o];
    out[m * O_DIM + o] = v;
}

extern "C" void kernel_launch(void* const* d_in, const int* in_sizes, int n_in,
                              void* d_out, int out_size, void* d_ws, size_t ws_size,
                              hipStream_t stream) {
    const float* x      = (const float*)d_in[0];
    const int*   qw     = (const int*)d_in[1];
    const float* scales = (const float*)d_in[2];
    const float* bias   = (const float*)d_in[3];
    float*       out    = (float*)d_out;
    float*       part   = (float*)d_ws;              // 16 x 32 x 11008 f32 = 22.5 MB

    // k1: streaming dequant-MFMA GEMM, split-major dispatch
    hipLaunchKernelGGL(gemm_kernel, dim3(NSPLIT, O_DIM / 64), dim3(256), 0, stream,
                       x, qw, scales, part);

    // k2: reduce partials + bias
    hipLaunchKernelGGL(reduce_kernel, dim3(O_DIM / 256, B_DIM), dim3(256), 0, stream,
                       part, bias, out);
}